// Round 17
// baseline (716.336 us; speedup 1.0000x reference)
//
#include <hip/hip_runtime.h>
#include <math.h>

#define N_NODES 10000
#define N_EDGES 100000
#define E_TOT   (N_EDGES + N_NODES)
#define PROJ    768
#define LN_EPS  1e-5f

typedef __attribute__((ext_vector_type(8))) short bf16x8;
typedef __attribute__((ext_vector_type(4))) short bf16x4;
typedef __attribute__((ext_vector_type(4))) float f32x4;

__device__ __forceinline__ float elu_f(float x){ return x > 0.f ? x : __expf(x) - 1.f; }
__device__ __forceinline__ float bf2f(unsigned short u){ return __uint_as_float(((unsigned int)u) << 16); }
__device__ __forceinline__ unsigned short f2bf(float f){
  unsigned int u = __float_as_uint(f);
  return (unsigned short)((u + 0x7FFFu + ((u >> 16) & 1u)) >> 16);
}

#define GLOAD16(gp, lp) __builtin_amdgcn_global_load_lds((const __attribute__((address_space(1))) void*)(gp), (__attribute__((address_space(3))) void*)(lp), 16, 0, 0)

// ---------------- CSR build (by dst, self loops appended) ----------------
__global__ void k_count(const int* __restrict__ ei, int* __restrict__ cnt){
  int e = blockIdx.x*blockDim.x + threadIdx.x;
  if (e >= E_TOT) return;
  int dst = (e < N_EDGES) ? ei[N_EDGES + e] : (e - N_EDGES);
  atomicAdd(&cnt[dst], 1);
}

__global__ void k_scan(const int* __restrict__ cnt, int* __restrict__ indptr, int* __restrict__ pos){
  __shared__ int s[1024];
  __shared__ int s_running;
  int t = threadIdx.x;
  if (t == 0) s_running = 0;
  __syncthreads();
  for (int base = 0; base < N_NODES; base += 1024){
    int v = (base + t < N_NODES) ? cnt[base + t] : 0;
    s[t] = v; __syncthreads();
    for (int off = 1; off < 1024; off <<= 1){
      int add = (t >= off) ? s[t - off] : 0;
      __syncthreads();
      s[t] += add;
      __syncthreads();
    }
    int total = s[1023];
    int run = s_running;
    if (base + t < N_NODES){
      int val = run + s[t] - v;
      indptr[base + t] = val;
      pos[base + t] = val;
    }
    __syncthreads();
    if (t == 0) s_running = run + total;
    __syncthreads();
  }
  if (t == 0) indptr[N_NODES] = s_running;
}

__global__ void k_fill(const int* __restrict__ ei, int* __restrict__ pos,
                       int* __restrict__ csr_src){
  int e = blockIdx.x*blockDim.x + threadIdx.x;
  if (e >= E_TOT) return;
  int s, d;
  if (e < N_EDGES){ s = ei[e]; d = ei[N_EDGES + e]; }
  else            { s = d = e - N_EDGES; }
  int p = atomicAdd(&pos[d], 1);
  csr_src[p] = s;
}

// merged fp32->bf16 converts: 4 segments (x, proj_W, uni_W, fg_W)
__global__ void k_f2bf_multi(const float4* __restrict__ s0, ushort4* __restrict__ d0, int n0,
                             const float4* __restrict__ s1, ushort4* __restrict__ d1, int n1,
                             const float4* __restrict__ s2, ushort4* __restrict__ d2, int n2,
                             const float4* __restrict__ s3, ushort4* __restrict__ d3, int n3){
  int i = blockIdx.x*blockDim.x + threadIdx.x;
  const float4* src; ushort4* dst; int idx;
  if (i < n0){ src = s0; dst = d0; idx = i; }
  else if (i < n0+n1){ src = s1; dst = d1; idx = i-n0; }
  else if (i < n0+n1+n2){ src = s2; dst = d2; idx = i-n0-n1; }
  else if (i < n0+n1+n2+n3){ src = s3; dst = d3; idx = i-n0-n1-n2; }
  else return;
  float4 v = src[idx];
  ushort4 o;
  o.x = f2bf(v.x); o.y = f2bf(v.y); o.z = f2bf(v.z); o.w = f2bf(v.w);
  dst[idx] = o;
}

// pack g1_W[4][768][768] + g2_W[4][192][768] -> per-layer [960][768] bf16
__global__ void k_pack_l1l2(const float* __restrict__ g1, const float* __restrict__ g2,
                            unsigned short* __restrict__ dst){
  int i = blockIdx.x*blockDim.x + threadIdx.x;
  if (i >= 737280) return;
  int layer = i / 184320;
  int off4  = i - layer*184320;
  float4 v;
  if (off4 < 147456) v = *((const float4*)(g1 + (size_t)layer*589824) + off4);
  else               v = *((const float4*)(g2 + (size_t)layer*147456) + (off4 - 147456));
  ushort4 o;
  o.x = f2bf(v.x); o.y = f2bf(v.y); o.z = f2bf(v.z); o.w = f2bf(v.w);
  ((ushort4*)(dst + (size_t)layer*737280))[off4] = o;
}

// ---------------- LayerNorm over 768, bf16 in -> bf16 out ----------------
__global__ void k_layernorm_bf(const unsigned short* __restrict__ x, const float* __restrict__ w,
                               const float* __restrict__ b, unsigned short* __restrict__ y){
  int n = blockIdx.x;
  int t = threadIdx.x;
  const unsigned short* xr = x + (size_t)n*PROJ;
  float v0=0.f, v1=0.f, v2=0.f, v3=0.f;
  if (t < 192){
    bf16x4 hv = *(const bf16x4*)(xr + t*4);
    v0 = bf2f((unsigned short)hv.x); v1 = bf2f((unsigned short)hv.y);
    v2 = bf2f((unsigned short)hv.z); v3 = bf2f((unsigned short)hv.w);
  }
  float s  = v0+v1+v2+v3;
  float s2 = v0*v0 + v1*v1 + v2*v2 + v3*v3;
  #pragma unroll
  for (int off = 32; off; off >>= 1){ s += __shfl_down(s, off); s2 += __shfl_down(s2, off); }
  __shared__ float rs[4], rs2[4];
  __shared__ float s_mean, s_rstd;
  int wid = t >> 6, lane = t & 63;
  if (lane == 0){ rs[wid] = s; rs2[wid] = s2; }
  __syncthreads();
  if (t == 0){
    float S  = rs[0]+rs[1]+rs[2]+rs[3];
    float S2 = rs2[0]+rs2[1]+rs2[2]+rs2[3];
    float m  = S * (1.f/768.f);
    float var = S2 * (1.f/768.f) - m*m;
    s_mean = m; s_rstd = rsqrtf(var + LN_EPS);
  }
  __syncthreads();
  if (t < 192){
    float m = s_mean, r = s_rstd;
    float4 wv = *(const float4*)&w[t*4];
    float4 bv = *(const float4*)&b[t*4];
    ushort4 o;
    o.x = f2bf((v0-m)*r*wv.x + bv.x);
    o.y = f2bf((v1-m)*r*wv.y + bv.y);
    o.z = f2bf((v2-m)*r*wv.z + bv.z);
    o.w = f2bf((v3-m)*r*wv.w + bv.w);
    *(ushort4*)(y + (size_t)n*PROJ + t*4) = o;
  }
}

// ---------------- bf16 MFMA GEMM: 128x64 tile, BK=32, 3-buffer rotation, ONE barrier/iter ----------------
// EPI 0: bf16 out; 1: bf16 elu(v+bias); 2: bf16 elu(v+bias+res_bf16)
template<int EPI>
__global__ __launch_bounds__(256, 8)
void k_gemm_mfma(const unsigned short* __restrict__ A, int lda,
                 const unsigned short* __restrict__ W,
                 unsigned short* __restrict__ C, int ldc,
                 int M, int N, int K,
                 const float* __restrict__ bias,
                 const unsigned short* __restrict__ res, int ldres, int NBN){
  __shared__ unsigned short As[3][128*32];
  __shared__ unsigned short Bs[3][64*32];
  const int tid = threadIdx.x;
  const int lane = tid & 63, wid = tid >> 6;
  const int wm = wid >> 1, wn = wid & 1;

  const int nwg = gridDim.x;
  const int q = nwg >> 3, r = nwg & 7;
  const int xcd = blockIdx.x & 7, o = blockIdx.x >> 3;
  const int swz = (xcd < r ? xcd*(q+1) : r*(q+1) + (xcd - r)*q) + o;
  const int bm = (swz / NBN) * 128;
  const int bn = (swz % NBN) * 64;

  const int srow = tid >> 2;
  const int sc   = (tid & 3) ^ ((tid >> 3) & 3);
  size_t ga0 = (size_t)min(bm + srow,      M-1)*lda + sc*8;
  size_t ga1 = (size_t)min(bm + 64 + srow, M-1)*lda + sc*8;
  size_t gb0 = (size_t)min(bn + srow,      N-1)*K   + sc*8;
  const int ldst = tid*8;

  f32x4 acc[4][2];
  #pragma unroll
  for (int i=0;i<4;i++)
    #pragma unroll
    for (int j=0;j<2;j++) acc[i][j] = (f32x4){0.f,0.f,0.f,0.f};

  const int rA = wm*64 + (lane & 15);
  const int rB = wn*32 + (lane & 15);
  const int cu = (((lane >> 4)) ^ (((lane & 15) >> 1) & 3)) * 8;

  const int NT = K >> 5;
  int bcur = 0;
  GLOAD16(A + ga0, &As[0][ldst]);
  GLOAD16(A + ga1, &As[0][2048 + ldst]);
  GLOAD16(W + gb0, &Bs[0][ldst]);

  for (int t = 0; t < NT; ++t){
    if (t + 1 < NT){
      int bst = bcur + 1; if (bst == 3) bst = 0;
      const int k0 = (t+1) << 5;
      GLOAD16(A + ga0 + k0, &As[bst][ldst]);
      GLOAD16(A + ga1 + k0, &As[bst][2048 + ldst]);
      GLOAD16(W + gb0 + k0, &Bs[bst][ldst]);
      asm volatile("s_waitcnt vmcnt(3)" ::: "memory");
    } else {
      asm volatile("s_waitcnt vmcnt(0)" ::: "memory");
    }
    __builtin_amdgcn_sched_barrier(0);
    __builtin_amdgcn_s_barrier();
    __builtin_amdgcn_sched_barrier(0);

    bf16x8 af[4], bfr[2];
    #pragma unroll
    for (int mi = 0; mi < 4; mi++)
      af[mi] = *(const bf16x8*)&As[bcur][(rA + mi*16)*32 + cu];
    #pragma unroll
    for (int ni = 0; ni < 2; ni++)
      bfr[ni] = *(const bf16x8*)&Bs[bcur][(rB + ni*16)*32 + cu];
    #pragma unroll
    for (int mi = 0; mi < 4; mi++)
      #pragma unroll
      for (int ni = 0; ni < 2; ni++)
        acc[mi][ni] = __builtin_amdgcn_mfma_f32_16x16x32_bf16(af[mi], bfr[ni], acc[mi][ni], 0,0,0);

    bcur += 1; if (bcur == 3) bcur = 0;
  }

  const int mrow0 = bm + wm*64 + ((lane>>4)<<2);
  const int ncol0 = bn + wn*32 + (lane & 15);
  #pragma unroll
  for (int mi=0; mi<4; mi++){
    #pragma unroll
    for (int rr=0; rr<4; rr++){
      int m = mrow0 + mi*16 + rr;
      if (m >= M) continue;
      #pragma unroll
      for (int ni=0; ni<2; ni++){
        int n = ncol0 + ni*16;
        float v = acc[mi][ni][rr];
        if (EPI == 1){
          v = elu_f(v + bias[n]);
        } else if (EPI == 2){
          v = elu_f(v + bias[n] + bf2f(res[(size_t)m*ldres + n]));
        }
        C[(size_t)m*ldc + n] = f2bf(v);
      }
    }
  }
}

// ---------------- merged per-layer attention coefficients (6 heads: 4x192 + 2x96) ----------------
__global__ void k_attn_coef6(const unsigned short* __restrict__ hlin,
                             const float* __restrict__ as1, const float* __restrict__ ad1,
                             const float* __restrict__ as2, const float* __restrict__ ad2,
                             float* __restrict__ als, float* __restrict__ ald){
  int n = blockIdx.x;
  int wid = threadIdx.x >> 6, lane = threadIdx.x & 63;
  int C    = wid < 4 ? 192 : 96;
  int base = wid < 4 ? wid*192 : 768 + (wid-4)*96;
  const float* as_ = wid < 4 ? as1 + wid*192 : as2 + (wid-4)*96;
  const float* ad_ = wid < 4 ? ad1 + wid*192 : ad2 + (wid-4)*96;
  float ss = 0.f, sd = 0.f;
  if (lane*4 < C){
    bf16x4 hv = *(const bf16x4*)(hlin + (size_t)n*960 + base + lane*4);
    float4 a1 = *(const float4*)&as_[lane*4];
    float4 a2 = *(const float4*)&ad_[lane*4];
    float h0 = bf2f((unsigned short)hv.x), h1 = bf2f((unsigned short)hv.y);
    float h2 = bf2f((unsigned short)hv.z), h3 = bf2f((unsigned short)hv.w);
    ss = h0*a1.x + h1*a1.y + h2*a1.z + h3*a1.w;
    sd = h0*a2.x + h1*a2.y + h2*a2.z + h3*a2.w;
  }
  #pragma unroll
  for (int off = 32; off; off >>= 1){ ss += __shfl_down(ss, off); sd += __shfl_down(sd, off); }
  if (lane == 0){ als[n*6 + wid] = ss; ald[n*6 + wid] = sd; }
}

// ---------------- final attention coefficients (8 heads x 128) ----------------
__global__ void k_attn_coef8(const unsigned short* __restrict__ hlin,
                             const float* __restrict__ a_src, const float* __restrict__ a_dst,
                             float* __restrict__ als, float* __restrict__ ald){
  int n = blockIdx.x;
  int wid = threadIdx.x >> 6, lane = threadIdx.x & 63;
  float ss = 0.f, sd = 0.f;
  if (lane < 32){
    bf16x4 hv = *(const bf16x4*)(hlin + (size_t)n*1024 + wid*128 + lane*4);
    float4 a1 = *(const float4*)&a_src[wid*128 + lane*4];
    float4 a2 = *(const float4*)&a_dst[wid*128 + lane*4];
    float h0 = bf2f((unsigned short)hv.x), h1 = bf2f((unsigned short)hv.y);
    float h2 = bf2f((unsigned short)hv.z), h3 = bf2f((unsigned short)hv.w);
    ss = h0*a1.x + h1*a1.y + h2*a1.z + h3*a1.w;
    sd = h0*a2.x + h1*a2.y + h2*a2.z + h3*a2.w;
  }
  #pragma unroll
  for (int off = 32; off; off >>= 1){ ss += __shfl_down(ss, off); sd += __shfl_down(sd, off); }
  if (lane == 0){ als[n*8 + wid] = ss; ald[n*8 + wid] = sd; }
}

// ---------------- one-wave-per-node attention: stats + alpha + gather, NO block sync ----------------
// block = 256 threads = 4 waves = 4 nodes. MODE 0: TOT=960, HT=6, bias+ELU -> bf16;
// MODE 1: TOT=1024, HT=8, head-mean -> f32 (per-wave LDS scratch).
template<int MODE>
__global__ __launch_bounds__(256)
void k_attn_node(const unsigned short* __restrict__ hlin, int ldh,
                 const float* __restrict__ als, const float* __restrict__ ald,
                 const int* __restrict__ indptr, const int* __restrict__ csr_src,
                 const float* __restrict__ b1, const float* __restrict__ b2,
                 void* __restrict__ outv, int ldo){
  constexpr int TOT = MODE ? 1024 : 960;
  constexpr int HT  = MODE ? 8 : 6;
  __shared__ float s_scr[4][MODE ? 1024 : 1];   // MODE1 head-mean scratch (per-wave slice)

  int wv = threadIdx.x >> 6, lane = threadIdx.x & 63;
  int n = blockIdx.x*4 + wv;
  if (n >= N_NODES) return;
  int beg = indptr[n], end = indptr[n+1];

  // ---- stats: all heads at once, lane-strided edges + butterfly (all lanes end identical)
  float m[HT], d[HT], aldv[HT];
  #pragma unroll
  for (int h = 0; h < HT; h++){ m[h] = -1e30f; d[h] = 0.f; aldv[h] = ald[n*HT + h]; }
  for (int e = beg + lane; e < end; e += 64){
    int s = csr_src[e];
    #pragma unroll
    for (int h = 0; h < HT; h++){
      float v = als[s*HT + h] + aldv[h];
      v = v > 0.f ? v : 0.2f*v;
      if (v > m[h]){ d[h] *= __expf(m[h] - v); m[h] = v; }
      d[h] += __expf(v - m[h]);
    }
  }
  #pragma unroll
  for (int off = 1; off < 64; off <<= 1){
    #pragma unroll
    for (int h = 0; h < HT; h++){
      float mo = __shfl_xor(m[h], off);
      float dd = __shfl_xor(d[h], off);
      float mn = fmaxf(m[h], mo);
      d[h] = d[h]*__expf(m[h] - mn) + dd*__expf(mo - mn);
      m[h] = mn;
    }
  }
  // per-lane head scalars (lane h owns head h), extracted with compile-time indices
  float mh = m[0], dh = 1.f/(d[0] + 1e-16f), av = aldv[0];
  #pragma unroll
  for (int h = 1; h < HT; h++){
    if (lane == h){ mh = m[h]; dh = 1.f/(d[h] + 1e-16f); av = aldv[h]; }
  }

  // head index per pass for this lane
  int hof[4];
  #pragma unroll
  for (int p = 0; p < 4; p++){
    int idx = (p*64 + lane)*4;
    hof[p] = MODE ? (idx >> 7) : (idx < 768 ? idx/192 : 4 + (idx-768)/96);
  }

  f32x4 acc[4];
  #pragma unroll
  for (int p = 0; p < 4; p++) acc[p] = (f32x4){0.f,0.f,0.f,0.f};

  // ---- gather: 2-edge unroll; lane reads contiguous bf16x4 per pass (512B/wave)
  int e = beg;
  for (; e + 1 < end; e += 2){
    int s0 = csr_src[e], s1 = csr_src[e+1];
    float al0 = 0.f, al1 = 0.f;
    if (lane < HT){
      float v0 = als[s0*HT + lane] + av; v0 = v0 > 0.f ? v0 : 0.2f*v0;
      al0 = __expf(v0 - mh)*dh;
      float v1 = als[s1*HT + lane] + av; v1 = v1 > 0.f ? v1 : 0.2f*v1;
      al1 = __expf(v1 - mh)*dh;
    }
    const bf16x4* r0 = (const bf16x4*)(hlin + (size_t)s0*ldh);
    const bf16x4* r1 = (const bf16x4*)(hlin + (size_t)s1*ldh);
    #pragma unroll
    for (int p = 0; p < 4; p++){
      int ch = p*64 + lane;
      if (TOT == 1024 || ch*4 < TOT){
        bf16x4 h0 = r0[ch], h1 = r1[ch];
        float a0 = __shfl(al0, hof[p]);
        float a1 = __shfl(al1, hof[p]);
        acc[p].x += bf2f((unsigned short)h0.x)*a0 + bf2f((unsigned short)h1.x)*a1;
        acc[p].y += bf2f((unsigned short)h0.y)*a0 + bf2f((unsigned short)h1.y)*a1;
        acc[p].z += bf2f((unsigned short)h0.z)*a0 + bf2f((unsigned short)h1.z)*a1;
        acc[p].w += bf2f((unsigned short)h0.w)*a0 + bf2f((unsigned short)h1.w)*a1;
      }
    }
  }
  for (; e < end; e++){
    int s0 = csr_src[e];
    float al0 = 0.f;
    if (lane < HT){
      float v0 = als[s0*HT + lane] + av; v0 = v0 > 0.f ? v0 : 0.2f*v0;
      al0 = __expf(v0 - mh)*dh;
    }
    const bf16x4* r0 = (const bf16x4*)(hlin + (size_t)s0*ldh);
    #pragma unroll
    for (int p = 0; p < 4; p++){
      int ch = p*64 + lane;
      if (TOT == 1024 || ch*4 < TOT){
        bf16x4 h0 = r0[ch];
        float a0 = __shfl(al0, hof[p]);
        acc[p].x += bf2f((unsigned short)h0.x)*a0;
        acc[p].y += bf2f((unsigned short)h0.y)*a0;
        acc[p].z += bf2f((unsigned short)h0.z)*a0;
        acc[p].w += bf2f((unsigned short)h0.w)*a0;
      }
    }
  }

  // ---- epilogue
  if (MODE == 0){
    unsigned short* out = (unsigned short*)outv;
    #pragma unroll
    for (int p = 0; p < 4; p++){
      int idx = (p*64 + lane)*4;
      if (idx < TOT){
        const float* bb = idx < 768 ? &b1[idx] : &b2[idx - 768];
        float4 bv = *(const float4*)bb;
        ushort4 o;
        o.x = f2bf(elu_f(acc[p].x + bv.x));
        o.y = f2bf(elu_f(acc[p].y + bv.y));
        o.z = f2bf(elu_f(acc[p].z + bv.z));
        o.w = f2bf(elu_f(acc[p].w + bv.w));
        *(ushort4*)(out + (size_t)n*ldo + idx) = o;
      }
    }
  } else {
    // head-mean via per-wave LDS slice (same-wave write->read, compiler inserts lgkm waits)
    #pragma unroll
    for (int p = 0; p < 4; p++)
      *(f32x4*)&s_scr[wv][(p*64 + lane)*4] = acc[p];
    float* out = (float*)outv;
    int c0 = lane*2, c1 = lane*2 + 1;
    float o0 = 0.f, o1 = 0.f;
    #pragma unroll
    for (int h = 0; h < 8; h++){
      o0 += s_scr[wv][h*128 + c0];
      o1 += s_scr[wv][h*128 + c1];
    }
    out[(size_t)n*ldo + c0] = o0*0.125f + b1[c0];
    out[(size_t)n*ldo + c1] = o1*0.125f + b1[c1];
  }
}

// ---------------- launch ----------------
extern "C" void kernel_launch(void* const* d_in, const int* in_sizes, int n_in,
                              void* d_out, int out_size, void* d_ws, size_t ws_size,
                              hipStream_t stream){
  const float* x      = (const float*)d_in[0];
  const int*   ei     = (const int*)  d_in[1];
  const float* proj_W = (const float*)d_in[2];
  const float* proj_b = (const float*)d_in[3];
  const float* norm_w = (const float*)d_in[4];
  const float* norm_b = (const float*)d_in[5];
  const float* g1_W   = (const float*)d_in[6];
  const float* g1_as  = (const float*)d_in[7];
  const float* g1_ad  = (const float*)d_in[8];
  const float* g1_b   = (const float*)d_in[9];
  const float* g2_W   = (const float*)d_in[10];
  const float* g2_as  = (const float*)d_in[11];
  const float* g2_ad  = (const float*)d_in[12];
  const float* g2_b   = (const float*)d_in[13];
  const float* uni_W  = (const float*)d_in[14];
  const float* uni_b  = (const float*)d_in[15];
  const float* fnorm_w= (const float*)d_in[16];
  const float* fnorm_b= (const float*)d_in[17];
  const float* fg_W   = (const float*)d_in[18];
  const float* fg_as  = (const float*)d_in[19];
  const float* fg_ad  = (const float*)d_in[20];
  const float* fg_b   = (const float*)d_in[21];

  float* w = (float*)d_ws;
  unsigned short* h  = (unsigned short*)w; w += 3840000;   // bf16 [10000,768] residual stream
  unsigned short* h2 = (unsigned short*)w; w += 3840000;
  unsigned short* linbuf = (unsigned short*)w; w += 5120000;  // bf16 [10000,1024]/[10000,960]
  unsigned short* hnb  = (unsigned short*)w; w += 3840000;
  unsigned short* catb = (unsigned short*)w; w += 4800000;
  unsigned short* wb   = (unsigned short*)w; w += 3489792;
  float* als   = w; w += 80000;   // [N,8] max
  float* ald   = w; w += 80000;
  int* iw = (int*)w;
  int* cnt     = iw; iw += 10016;
  int* indptr  = iw; iw += 10016;
  int* pos     = iw; iw += 10016;
  int* csr_src = iw; iw += 110016;

  unsigned short* wb_proj = wb;
  unsigned short* wb_l12  = wb_proj + 294912;   // 4 x [960][768]
  unsigned short* wb_uni  = wb_l12 + 2949120;
  unsigned short* wb_fg   = wb_uni + 2949120;

  // CSR
  hipMemsetAsync(cnt, 0, N_NODES*sizeof(int), stream);
  k_count<<<(E_TOT+255)/256, 256, 0, stream>>>(ei, cnt);
  k_scan<<<1, 1024, 0, stream>>>(cnt, indptr, pos);
  k_fill<<<(E_TOT+255)/256, 256, 0, stream>>>(ei, pos, csr_src);

  // fp32 -> bf16 converts: one merged dispatch + the l1/l2 pack
  k_f2bf_multi<<<(1967616+255)/256, 256, 0, stream>>>(
      (const float4*)x, (ushort4*)hnb, 960000,
      (const float4*)proj_W, (ushort4*)wb_proj, 73728,
      (const float4*)uni_W, (ushort4*)wb_uni, 737280,
      (const float4*)fg_W, (ushort4*)wb_fg, 196608);
  k_pack_l1l2<<<(737280+255)/256, 256, 0, stream>>>(g1_W, g2_W, wb_l12);

  dim3 blk(256);

  // h = elu(x @ proj_W.T + proj_b)   [N=768 -> NBN=12], bf16 out
  k_gemm_mfma<1><<<dim3(79*12), blk, 0, stream>>>(hnb, 384, wb_proj, h, 768, N_NODES, 768, 384, proj_b, nullptr, 0, 12);

  unsigned short* cur = h;
  unsigned short* oth = h2;
  for (int i = 0; i < 4; i++){
    k_layernorm_bf<<<N_NODES, 256, 0, stream>>>(cur, norm_w + i*768, norm_b + i*768, hnb);
    // combined [g1 | g2] GEMM: N = 960 -> NBN=15
    k_gemm_mfma<0><<<dim3(79*15), blk, 0, stream>>>(hnb, 768, wb_l12 + (size_t)i*737280, linbuf, 960, N_NODES, 960, 768, nullptr, nullptr, 0, 15);
    k_attn_coef6<<<N_NODES, 384, 0, stream>>>(linbuf, g1_as + i*768, g1_ad + i*768, g2_as + i*192, g2_ad + i*192, als, ald);
    k_attn_node<0><<<dim3(2500), blk, 0, stream>>>(linbuf, 960, als, ald, indptr, csr_src, g1_b + i*768, g2_b + i*192, catb, 960);
    // h = elu(res + cat @ uni_W.T + uni_b)  [N=768 -> NBN=12], bf16 res + bf16 out
    k_gemm_mfma<2><<<dim3(79*12), blk, 0, stream>>>(catb, 960, wb_uni + (size_t)i*737280, oth, 768, N_NODES, 768, 960, uni_b + i*768, cur, 768, 12);
    unsigned short* t = cur; cur = oth; oth = t;
  }

  k_layernorm_bf<<<N_NODES, 256, 0, stream>>>(cur, fnorm_w, fnorm_b, hnb);
  // final GEMM: N=1024 -> NBN=16
  k_gemm_mfma<0><<<dim3(79*16), blk, 0, stream>>>(hnb, 768, wb_fg, linbuf, 1024, N_NODES, 1024, 768, nullptr, nullptr, 0, 16);
  k_attn_coef8<<<N_NODES, 512, 0, stream>>>(linbuf, fg_as, fg_ad, als, ald);
  k_attn_node<1><<<dim3(2500), blk, 0, stream>>>(linbuf, 1024, als, ald, indptr, csr_src, fg_b, nullptr, d_out, 128);
}

// Round 18
// 696.041 us; speedup vs baseline: 1.0292x; 1.0292x over previous
//
#include <hip/hip_runtime.h>
#include <math.h>

#define N_NODES 10000
#define N_EDGES 100000
#define E_TOT   (N_EDGES + N_NODES)
#define PROJ    768
#define LN_EPS  1e-5f

typedef __attribute__((ext_vector_type(8))) short bf16x8;
typedef __attribute__((ext_vector_type(4))) short bf16x4;
typedef __attribute__((ext_vector_type(4))) float f32x4;

__device__ __forceinline__ float elu_f(float x){ return x > 0.f ? x : __expf(x) - 1.f; }
__device__ __forceinline__ float bf2f(unsigned short u){ return __uint_as_float(((unsigned int)u) << 16); }
__device__ __forceinline__ unsigned short f2bf(float f){
  unsigned int u = __float_as_uint(f);
  return (unsigned short)((u + 0x7FFFu + ((u >> 16) & 1u)) >> 16);
}

#define GLOAD16(gp, lp) __builtin_amdgcn_global_load_lds((const __attribute__((address_space(1))) void*)(gp), (__attribute__((address_space(3))) void*)(lp), 16, 0, 0)

// ---------------- CSR build (by dst, self loops appended) ----------------
__global__ void k_count(const int* __restrict__ ei, int* __restrict__ cnt){
  int e = blockIdx.x*blockDim.x + threadIdx.x;
  if (e >= E_TOT) return;
  int dst = (e < N_EDGES) ? ei[N_EDGES + e] : (e - N_EDGES);
  atomicAdd(&cnt[dst], 1);
}

__global__ void k_scan(const int* __restrict__ cnt, int* __restrict__ indptr, int* __restrict__ pos){
  __shared__ int s[1024];
  __shared__ int s_running;
  int t = threadIdx.x;
  if (t == 0) s_running = 0;
  __syncthreads();
  for (int base = 0; base < N_NODES; base += 1024){
    int v = (base + t < N_NODES) ? cnt[base + t] : 0;
    s[t] = v; __syncthreads();
    for (int off = 1; off < 1024; off <<= 1){
      int add = (t >= off) ? s[t - off] : 0;
      __syncthreads();
      s[t] += add;
      __syncthreads();
    }
    int total = s[1023];
    int run = s_running;
    if (base + t < N_NODES){
      int val = run + s[t] - v;
      indptr[base + t] = val;
      pos[base + t] = val;
    }
    __syncthreads();
    if (t == 0) s_running = run + total;
    __syncthreads();
  }
  if (t == 0) indptr[N_NODES] = s_running;
}

__global__ void k_fill(const int* __restrict__ ei, int* __restrict__ pos,
                       int* __restrict__ csr_src){
  int e = blockIdx.x*blockDim.x + threadIdx.x;
  if (e >= E_TOT) return;
  int s, d;
  if (e < N_EDGES){ s = ei[e]; d = ei[N_EDGES + e]; }
  else            { s = d = e - N_EDGES; }
  int p = atomicAdd(&pos[d], 1);
  csr_src[p] = s;
}

// merged fp32->bf16 converts: 4 segments (x, proj_W, uni_W, fg_W)
__global__ void k_f2bf_multi(const float4* __restrict__ s0, ushort4* __restrict__ d0, int n0,
                             const float4* __restrict__ s1, ushort4* __restrict__ d1, int n1,
                             const float4* __restrict__ s2, ushort4* __restrict__ d2, int n2,
                             const float4* __restrict__ s3, ushort4* __restrict__ d3, int n3){
  int i = blockIdx.x*blockDim.x + threadIdx.x;
  const float4* src; ushort4* dst; int idx;
  if (i < n0){ src = s0; dst = d0; idx = i; }
  else if (i < n0+n1){ src = s1; dst = d1; idx = i-n0; }
  else if (i < n0+n1+n2){ src = s2; dst = d2; idx = i-n0-n1; }
  else if (i < n0+n1+n2+n3){ src = s3; dst = d3; idx = i-n0-n1-n2; }
  else return;
  float4 v = src[idx];
  ushort4 o;
  o.x = f2bf(v.x); o.y = f2bf(v.y); o.z = f2bf(v.z); o.w = f2bf(v.w);
  dst[idx] = o;
}

// pack g1_W[4][768][768] + g2_W[4][192][768] -> per-layer [960][768] bf16
__global__ void k_pack_l1l2(const float* __restrict__ g1, const float* __restrict__ g2,
                            unsigned short* __restrict__ dst){
  int i = blockIdx.x*blockDim.x + threadIdx.x;
  if (i >= 737280) return;
  int layer = i / 184320;
  int off4  = i - layer*184320;
  float4 v;
  if (off4 < 147456) v = *((const float4*)(g1 + (size_t)layer*589824) + off4);
  else               v = *((const float4*)(g2 + (size_t)layer*147456) + (off4 - 147456));
  ushort4 o;
  o.x = f2bf(v.x); o.y = f2bf(v.y); o.z = f2bf(v.z); o.w = f2bf(v.w);
  ((ushort4*)(dst + (size_t)layer*737280))[off4] = o;
}

// ---------------- LayerNorm over 768, bf16 in -> bf16 out ----------------
__global__ void k_layernorm_bf(const unsigned short* __restrict__ x, const float* __restrict__ w,
                               const float* __restrict__ b, unsigned short* __restrict__ y){
  int n = blockIdx.x;
  int t = threadIdx.x;
  const unsigned short* xr = x + (size_t)n*PROJ;
  float v0=0.f, v1=0.f, v2=0.f, v3=0.f;
  if (t < 192){
    bf16x4 hv = *(const bf16x4*)(xr + t*4);
    v0 = bf2f((unsigned short)hv.x); v1 = bf2f((unsigned short)hv.y);
    v2 = bf2f((unsigned short)hv.z); v3 = bf2f((unsigned short)hv.w);
  }
  float s  = v0+v1+v2+v3;
  float s2 = v0*v0 + v1*v1 + v2*v2 + v3*v3;
  #pragma unroll
  for (int off = 32; off; off >>= 1){ s += __shfl_down(s, off); s2 += __shfl_down(s2, off); }
  __shared__ float rs[4], rs2[4];
  __shared__ float s_mean, s_rstd;
  int wid = t >> 6, lane = t & 63;
  if (lane == 0){ rs[wid] = s; rs2[wid] = s2; }
  __syncthreads();
  if (t == 0){
    float S  = rs[0]+rs[1]+rs[2]+rs[3];
    float S2 = rs2[0]+rs2[1]+rs2[2]+rs2[3];
    float m  = S * (1.f/768.f);
    float var = S2 * (1.f/768.f) - m*m;
    s_mean = m; s_rstd = rsqrtf(var + LN_EPS);
  }
  __syncthreads();
  if (t < 192){
    float m = s_mean, r = s_rstd;
    float4 wv = *(const float4*)&w[t*4];
    float4 bv = *(const float4*)&b[t*4];
    ushort4 o;
    o.x = f2bf((v0-m)*r*wv.x + bv.x);
    o.y = f2bf((v1-m)*r*wv.y + bv.y);
    o.z = f2bf((v2-m)*r*wv.z + bv.z);
    o.w = f2bf((v3-m)*r*wv.w + bv.w);
    *(ushort4*)(y + (size_t)n*PROJ + t*4) = o;
  }
}

// ---------------- bf16 MFMA GEMM: 128x64 tile, BK=32, 3-buffer rotation, ONE barrier/iter ----------------
// EPI 0: bf16 out; 1: bf16 elu(v+bias); 2: bf16 elu(v+bias+res_bf16)
template<int EPI>
__global__ __launch_bounds__(256, 8)
void k_gemm_mfma(const unsigned short* __restrict__ A, int lda,
                 const unsigned short* __restrict__ W,
                 unsigned short* __restrict__ C, int ldc,
                 int M, int N, int K,
                 const float* __restrict__ bias,
                 const unsigned short* __restrict__ res, int ldres, int NBN){
  __shared__ unsigned short As[3][128*32];
  __shared__ unsigned short Bs[3][64*32];
  const int tid = threadIdx.x;
  const int lane = tid & 63, wid = tid >> 6;
  const int wm = wid >> 1, wn = wid & 1;

  const int nwg = gridDim.x;
  const int q = nwg >> 3, r = nwg & 7;
  const int xcd = blockIdx.x & 7, o = blockIdx.x >> 3;
  const int swz = (xcd < r ? xcd*(q+1) : r*(q+1) + (xcd - r)*q) + o;
  const int bm = (swz / NBN) * 128;
  const int bn = (swz % NBN) * 64;

  const int srow = tid >> 2;
  const int sc   = (tid & 3) ^ ((tid >> 3) & 3);
  size_t ga0 = (size_t)min(bm + srow,      M-1)*lda + sc*8;
  size_t ga1 = (size_t)min(bm + 64 + srow, M-1)*lda + sc*8;
  size_t gb0 = (size_t)min(bn + srow,      N-1)*K   + sc*8;
  const int ldst = tid*8;

  f32x4 acc[4][2];
  #pragma unroll
  for (int i=0;i<4;i++)
    #pragma unroll
    for (int j=0;j<2;j++) acc[i][j] = (f32x4){0.f,0.f,0.f,0.f};

  const int rA = wm*64 + (lane & 15);
  const int rB = wn*32 + (lane & 15);
  const int cu = (((lane >> 4)) ^ (((lane & 15) >> 1) & 3)) * 8;

  const int NT = K >> 5;
  int bcur = 0;
  GLOAD16(A + ga0, &As[0][ldst]);
  GLOAD16(A + ga1, &As[0][2048 + ldst]);
  GLOAD16(W + gb0, &Bs[0][ldst]);

  for (int t = 0; t < NT; ++t){
    if (t + 1 < NT){
      int bst = bcur + 1; if (bst == 3) bst = 0;
      const int k0 = (t+1) << 5;
      GLOAD16(A + ga0 + k0, &As[bst][ldst]);
      GLOAD16(A + ga1 + k0, &As[bst][2048 + ldst]);
      GLOAD16(W + gb0 + k0, &Bs[bst][ldst]);
      asm volatile("s_waitcnt vmcnt(3)" ::: "memory");
    } else {
      asm volatile("s_waitcnt vmcnt(0)" ::: "memory");
    }
    __builtin_amdgcn_sched_barrier(0);
    __builtin_amdgcn_s_barrier();
    __builtin_amdgcn_sched_barrier(0);

    bf16x8 af[4], bfr[2];
    #pragma unroll
    for (int mi = 0; mi < 4; mi++)
      af[mi] = *(const bf16x8*)&As[bcur][(rA + mi*16)*32 + cu];
    #pragma unroll
    for (int ni = 0; ni < 2; ni++)
      bfr[ni] = *(const bf16x8*)&Bs[bcur][(rB + ni*16)*32 + cu];
    #pragma unroll
    for (int mi = 0; mi < 4; mi++)
      #pragma unroll
      for (int ni = 0; ni < 2; ni++)
        acc[mi][ni] = __builtin_amdgcn_mfma_f32_16x16x32_bf16(af[mi], bfr[ni], acc[mi][ni], 0,0,0);

    bcur += 1; if (bcur == 3) bcur = 0;
  }

  const int mrow0 = bm + wm*64 + ((lane>>4)<<2);
  const int ncol0 = bn + wn*32 + (lane & 15);
  #pragma unroll
  for (int mi=0; mi<4; mi++){
    #pragma unroll
    for (int rr=0; rr<4; rr++){
      int m = mrow0 + mi*16 + rr;
      if (m >= M) continue;
      #pragma unroll
      for (int ni=0; ni<2; ni++){
        int n = ncol0 + ni*16;
        float v = acc[mi][ni][rr];
        if (EPI == 1){
          v = elu_f(v + bias[n]);
        } else if (EPI == 2){
          v = elu_f(v + bias[n] + bf2f(res[(size_t)m*ldres + n]));
        }
        C[(size_t)m*ldc + n] = f2bf(v);
      }
    }
  }
}

// ---------------- merged per-layer attention coefficients (6 heads: 4x192 + 2x96) ----------------
__global__ void k_attn_coef6(const unsigned short* __restrict__ hlin,
                             const float* __restrict__ as1, const float* __restrict__ ad1,
                             const float* __restrict__ as2, const float* __restrict__ ad2,
                             float* __restrict__ als, float* __restrict__ ald){
  int n = blockIdx.x;
  int wid = threadIdx.x >> 6, lane = threadIdx.x & 63;
  int C    = wid < 4 ? 192 : 96;
  int base = wid < 4 ? wid*192 : 768 + (wid-4)*96;
  const float* as_ = wid < 4 ? as1 + wid*192 : as2 + (wid-4)*96;
  const float* ad_ = wid < 4 ? ad1 + wid*192 : ad2 + (wid-4)*96;
  float ss = 0.f, sd = 0.f;
  if (lane*4 < C){
    bf16x4 hv = *(const bf16x4*)(hlin + (size_t)n*960 + base + lane*4);
    float4 a1 = *(const float4*)&as_[lane*4];
    float4 a2 = *(const float4*)&ad_[lane*4];
    float h0 = bf2f((unsigned short)hv.x), h1 = bf2f((unsigned short)hv.y);
    float h2 = bf2f((unsigned short)hv.z), h3 = bf2f((unsigned short)hv.w);
    ss = h0*a1.x + h1*a1.y + h2*a1.z + h3*a1.w;
    sd = h0*a2.x + h1*a2.y + h2*a2.z + h3*a2.w;
  }
  #pragma unroll
  for (int off = 32; off; off >>= 1){ ss += __shfl_down(ss, off); sd += __shfl_down(sd, off); }
  if (lane == 0){ als[n*6 + wid] = ss; ald[n*6 + wid] = sd; }
}

// ---------------- final attention coefficients (8 heads x 128) ----------------
__global__ void k_attn_coef8(const unsigned short* __restrict__ hlin,
                             const float* __restrict__ a_src, const float* __restrict__ a_dst,
                             float* __restrict__ als, float* __restrict__ ald){
  int n = blockIdx.x;
  int wid = threadIdx.x >> 6, lane = threadIdx.x & 63;
  float ss = 0.f, sd = 0.f;
  if (lane < 32){
    bf16x4 hv = *(const bf16x4*)(hlin + (size_t)n*1024 + wid*128 + lane*4);
    float4 a1 = *(const float4*)&a_src[wid*128 + lane*4];
    float4 a2 = *(const float4*)&a_dst[wid*128 + lane*4];
    float h0 = bf2f((unsigned short)hv.x), h1 = bf2f((unsigned short)hv.y);
    float h2 = bf2f((unsigned short)hv.z), h3 = bf2f((unsigned short)hv.w);
    ss = h0*a1.x + h1*a1.y + h2*a1.z + h3*a1.w;
    sd = h0*a2.x + h1*a2.y + h2*a2.z + h3*a2.w;
  }
  #pragma unroll
  for (int off = 32; off; off >>= 1){ ss += __shfl_down(ss, off); sd += __shfl_down(sd, off); }
  if (lane == 0){ als[n*8 + wid] = ss; ald[n*8 + wid] = sd; }
}

// ---------------- fused per-node attention: stats (+logit cache) + alpha (LDS) + gather ----------------
// MODE 0: layer (TOT=960, HT=6, bias+ELU -> bf16); MODE 1: final (TOT=1024, HT=8, head-mean -> f32)
template<int MODE>
__global__ __launch_bounds__(256)
void k_attn_fused(const unsigned short* __restrict__ hlin, int ldh,
                  const float* __restrict__ als, const float* __restrict__ ald,
                  const int* __restrict__ indptr, const int* __restrict__ csr_src,
                  const float* __restrict__ b1, const float* __restrict__ b2,
                  void* __restrict__ outv, int ldo){
  constexpr int TOT = MODE ? 1024 : 960;
  constexpr int HT  = MODE ? 8 : 6;
  constexpr int CH8 = TOT/8;              // 128 / 120
  constexpr int CPL = (CH8 + 63)/64;      // 2
  int n = blockIdx.x;
  int tid = threadIdx.x;
  int wv = tid >> 6, lane = tid & 63;
  int beg = indptr[n], end = indptr[n+1], deg = end - beg;

  __shared__ float s_m[HT], s_dinv[HT], s_ald[HT];
  __shared__ float s_alpha[64*HT];        // doubles as logit cache for the first 64-edge chunk
  __shared__ int   s_src[64];
  __shared__ float s_red[4][TOT];

  // ---- stage 1: per-head online softmax stats; cache first-chunk logits in s_alpha
  for (int h = wv; h < HT; h += 4){
    float aldv = ald[n*HT + h];
    float m = -1e30f, d = 0.f;
    int e = beg + lane;
    if (e < end){
      int s = csr_src[e];
      float v = als[s*HT + h] + aldv;
      v = v > 0.f ? v : 0.2f*v;
      s_alpha[lane*HT + h] = v;          // logit cache (chunk 0)
      m = v; d = 1.f;
      for (e += 64; e < end; e += 64){
        int s2 = csr_src[e];
        float v2 = als[s2*HT + h] + aldv;
        v2 = v2 > 0.f ? v2 : 0.2f*v2;
        if (v2 > m){ d *= __expf(m - v2); m = v2; }
        d += __expf(v2 - m);
      }
    }
    #pragma unroll
    for (int off = 1; off < 64; off <<= 1){
      float mo_ = __shfl_xor(m, off);
      float dd  = __shfl_xor(d, off);
      float mn  = fmaxf(m, mo_);
      d = d*__expf(m - mn) + dd*__expf(mo_ - mn);
      m = mn;
    }
    if (lane == 0){ s_m[h] = m; s_dinv[h] = 1.f/(d + 1e-16f); s_ald[h] = aldv; }
  }

  int hof[CPL];
  #pragma unroll
  for (int p = 0; p < CPL; p++){
    int idx = (lane + p*64)*8;
    hof[p] = MODE ? (idx >> 7) : (idx < 768 ? idx/192 : 4 + (idx-768)/96);
  }

  f32x4 accA[CPL], accB[CPL];
  #pragma unroll
  for (int p = 0; p < CPL; p++){ accA[p] = (f32x4){0,0,0,0}; accB[p] = (f32x4){0,0,0,0}; }

  // ---- stage 2: per-chunk alpha (LDS) + edge-parallel gather (2-edge unroll)
  for (int base = 0; base < deg; base += 64){
    int chunk = min(64, deg - base);
    __syncthreads();                    // closes stage-1 (and prev chunk) LDS use
    if (tid < chunk) s_src[tid] = csr_src[beg + base + tid];
    __syncthreads();
    if (base == 0){
      // logits already cached in s_alpha; in-place transform (same thread reads & writes element i)
      for (int i = tid; i < chunk*HT; i += 256){
        int h = i - (i/HT)*HT;
        s_alpha[i] = __expf(s_alpha[i] - s_m[h]) * s_dinv[h];
      }
    } else {
      for (int i = tid; i < chunk*HT; i += 256){
        int e = i / HT, h = i - e*HT;
        float v = als[s_src[e]*HT + h] + s_ald[h];
        v = v > 0.f ? v : 0.2f*v;
        s_alpha[i] = __expf(v - s_m[h]) * s_dinv[h];
      }
    }
    __syncthreads();

    int e = wv;
    for (; e + 4 < chunk; e += 8){
      int s0 = s_src[e], s1 = s_src[e+4];
      const bf16x8* hr0 = (const bf16x8*)(hlin + (size_t)s0*ldh);
      const bf16x8* hr1 = (const bf16x8*)(hlin + (size_t)s1*ldh);
      const float* ae0 = &s_alpha[e*HT];
      const float* ae1 = &s_alpha[(e+4)*HT];
      bf16x8 hv0[CPL], hv1[CPL];
      #pragma unroll
      for (int p = 0; p < CPL; p++){
        int ch = lane + p*64;
        if (CH8 % 64 == 0 || ch < CH8){ hv0[p] = hr0[ch]; hv1[p] = hr1[ch]; }
      }
      #pragma unroll
      for (int p = 0; p < CPL; p++){
        int ch = lane + p*64;
        if (CH8 % 64 == 0 || ch < CH8){
          float a0 = ae0[hof[p]], a1 = ae1[hof[p]];
          accA[p].x += bf2f((unsigned short)hv0[p][0])*a0 + bf2f((unsigned short)hv1[p][0])*a1;
          accA[p].y += bf2f((unsigned short)hv0[p][1])*a0 + bf2f((unsigned short)hv1[p][1])*a1;
          accA[p].z += bf2f((unsigned short)hv0[p][2])*a0 + bf2f((unsigned short)hv1[p][2])*a1;
          accA[p].w += bf2f((unsigned short)hv0[p][3])*a0 + bf2f((unsigned short)hv1[p][3])*a1;
          accB[p].x += bf2f((unsigned short)hv0[p][4])*a0 + bf2f((unsigned short)hv1[p][4])*a1;
          accB[p].y += bf2f((unsigned short)hv0[p][5])*a0 + bf2f((unsigned short)hv1[p][5])*a1;
          accB[p].z += bf2f((unsigned short)hv0[p][6])*a0 + bf2f((unsigned short)hv1[p][6])*a1;
          accB[p].w += bf2f((unsigned short)hv0[p][7])*a0 + bf2f((unsigned short)hv1[p][7])*a1;
        }
      }
    }
    for (; e < chunk; e += 4){
      int s = s_src[e];
      const bf16x8* hr = (const bf16x8*)(hlin + (size_t)s*ldh);
      const float* ae = &s_alpha[e*HT];
      #pragma unroll
      for (int p = 0; p < CPL; p++){
        int ch = lane + p*64;
        if (CH8 % 64 == 0 || ch < CH8){
          float al = ae[hof[p]];
          bf16x8 hv = hr[ch];
          accA[p].x += bf2f((unsigned short)hv[0])*al;
          accA[p].y += bf2f((unsigned short)hv[1])*al;
          accA[p].z += bf2f((unsigned short)hv[2])*al;
          accA[p].w += bf2f((unsigned short)hv[3])*al;
          accB[p].x += bf2f((unsigned short)hv[4])*al;
          accB[p].y += bf2f((unsigned short)hv[5])*al;
          accB[p].z += bf2f((unsigned short)hv[6])*al;
          accB[p].w += bf2f((unsigned short)hv[7])*al;
        }
      }
    }
  }

  #pragma unroll
  for (int p = 0; p < CPL; p++){
    int ch = lane + p*64;
    if (CH8 % 64 == 0 || ch < CH8){
      *(f32x4*)&s_red[wv][ch*8]     = accA[p];
      *(f32x4*)&s_red[wv][ch*8 + 4] = accB[p];
    }
  }
  __syncthreads();

  // ---- stage 3: cross-wave reduce + epilogue
  if (MODE == 0){
    unsigned short* out = (unsigned short*)outv;
    #pragma unroll
    for (int qq = 0; qq < 4; qq++){
      int idx = tid + qq*256;
      if (idx < TOT){
        float bb = idx < 768 ? b1[idx] : b2[idx - 768];
        float v = s_red[0][idx] + s_red[1][idx] + s_red[2][idx] + s_red[3][idx] + bb;
        out[(size_t)n*ldo + idx] = f2bf(elu_f(v));
      }
    }
  } else {
    float* out = (float*)outv;
    if (tid < 128){
      float v = 0.f;
      #pragma unroll
      for (int h = 0; h < 8; h++){
        int idx = h*128 + tid;
        v += s_red[0][idx] + s_red[1][idx] + s_red[2][idx] + s_red[3][idx];
      }
      out[(size_t)n*ldo + tid] = v*0.125f + b1[tid];
    }
  }
}

// ---------------- launch ----------------
extern "C" void kernel_launch(void* const* d_in, const int* in_sizes, int n_in,
                              void* d_out, int out_size, void* d_ws, size_t ws_size,
                              hipStream_t stream){
  const float* x      = (const float*)d_in[0];
  const int*   ei     = (const int*)  d_in[1];
  const float* proj_W = (const float*)d_in[2];
  const float* proj_b = (const float*)d_in[3];
  const float* norm_w = (const float*)d_in[4];
  const float* norm_b = (const float*)d_in[5];
  const float* g1_W   = (const float*)d_in[6];
  const float* g1_as  = (const float*)d_in[7];
  const float* g1_ad  = (const float*)d_in[8];
  const float* g1_b   = (const float*)d_in[9];
  const float* g2_W   = (const float*)d_in[10];
  const float* g2_as  = (const float*)d_in[11];
  const float* g2_ad  = (const float*)d_in[12];
  const float* g2_b   = (const float*)d_in[13];
  const float* uni_W  = (const float*)d_in[14];
  const float* uni_b  = (const float*)d_in[15];
  const float* fnorm_w= (const float*)d_in[16];
  const float* fnorm_b= (const float*)d_in[17];
  const float* fg_W   = (const float*)d_in[18];
  const float* fg_as  = (const float*)d_in[19];
  const float* fg_ad  = (const float*)d_in[20];
  const float* fg_b   = (const float*)d_in[21];

  float* w = (float*)d_ws;
  unsigned short* h  = (unsigned short*)w; w += 3840000;   // bf16 [10000,768] residual stream
  unsigned short* h2 = (unsigned short*)w; w += 3840000;
  unsigned short* linbuf = (unsigned short*)w; w += 5120000;  // bf16 [10000,1024]/[10000,960]
  unsigned short* hnb  = (unsigned short*)w; w += 3840000;
  unsigned short* catb = (unsigned short*)w; w += 4800000;
  unsigned short* wb   = (unsigned short*)w; w += 3489792;
  float* als   = w; w += 80000;   // [N,8] max
  float* ald   = w; w += 80000;
  int* iw = (int*)w;
  int* cnt     = iw; iw += 10016;
  int* indptr  = iw; iw += 10016;
  int* pos     = iw; iw += 10016;
  int* csr_src = iw; iw += 110016;

  unsigned short* wb_proj = wb;
  unsigned short* wb_l12  = wb_proj + 294912;   // 4 x [960][768]
  unsigned short* wb_uni  = wb_l12 + 2949120;
  unsigned short* wb_fg   = wb_uni + 2949120;

  // CSR
  hipMemsetAsync(cnt, 0, N_NODES*sizeof(int), stream);
  k_count<<<(E_TOT+255)/256, 256, 0, stream>>>(ei, cnt);
  k_scan<<<1, 1024, 0, stream>>>(cnt, indptr, pos);
  k_fill<<<(E_TOT+255)/256, 256, 0, stream>>>(ei, pos, csr_src);

  // fp32 -> bf16 converts: one merged dispatch + the l1/l2 pack
  k_f2bf_multi<<<(1967616+255)/256, 256, 0, stream>>>(
      (const float4*)x, (ushort4*)hnb, 960000,
      (const float4*)proj_W, (ushort4*)wb_proj, 73728,
      (const float4*)uni_W, (ushort4*)wb_uni, 737280,
      (const float4*)fg_W, (ushort4*)wb_fg, 196608);
  k_pack_l1l2<<<(737280+255)/256, 256, 0, stream>>>(g1_W, g2_W, wb_l12);

  dim3 blk(256);

  // h = elu(x @ proj_W.T + proj_b)   [N=768 -> NBN=12], bf16 out
  k_gemm_mfma<1><<<dim3(79*12), blk, 0, stream>>>(hnb, 384, wb_proj, h, 768, N_NODES, 768, 384, proj_b, nullptr, 0, 12);

  unsigned short* cur = h;
  unsigned short* oth = h2;
  for (int i = 0; i < 4; i++){
    k_layernorm_bf<<<N_NODES, 256, 0, stream>>>(cur, norm_w + i*768, norm_b + i*768, hnb);
    // combined [g1 | g2] GEMM: N = 960 -> NBN=15
    k_gemm_mfma<0><<<dim3(79*15), blk, 0, stream>>>(hnb, 768, wb_l12 + (size_t)i*737280, linbuf, 960, N_NODES, 960, 768, nullptr, nullptr, 0, 15);
    k_attn_coef6<<<N_NODES, 384, 0, stream>>>(linbuf, g1_as + i*768, g1_ad + i*768, g2_as + i*192, g2_ad + i*192, als, ald);
    k_attn_fused<0><<<N_NODES, 256, 0, stream>>>(linbuf, 960, als, ald, indptr, csr_src, g1_b + i*768, g2_b + i*192, catb, 960);
    // h = elu(res + cat @ uni_W.T + uni_b)  [N=768 -> NBN=12], bf16 res + bf16 out
    k_gemm_mfma<2><<<dim3(79*12), blk, 0, stream>>>(catb, 960, wb_uni + (size_t)i*737280, oth, 768, N_NODES, 768, 960, uni_b + i*768, cur, 768, 12);
    unsigned short* t = cur; cur = oth; oth = t;
  }

  k_layernorm_bf<<<N_NODES, 256, 0, stream>>>(cur, fnorm_w, fnorm_b, hnb);
  // final GEMM: N=1024 -> NBN=16
  k_gemm_mfma<0><<<dim3(79*16), blk, 0, stream>>>(hnb, 768, wb_fg, linbuf, 1024, N_NODES, 1024, 768, nullptr, nullptr, 0, 16);
  k_attn_coef8<<<N_NODES, 512, 0, stream>>>(linbuf, fg_as, fg_ad, als, ald);
  k_attn_fused<1><<<N_NODES, 256, 0, stream>>>(linbuf, 1024, als, ald, indptr, csr_src, fg_b, nullptr, d_out, 128);
}